// Round 6
// baseline (550.579 us; speedup 1.0000x reference)
//
#include <hip/hip_runtime.h>
#include <hip/hip_bf16.h>

// ExpertODEEnsemble: E=8, D=64, H=512, B=32768.
// R6: 4-wave blocks, 32-row tiles, M=128/wave x N=32 (1 ds_read per 4 MFMA),
// 4 blocks/CU -> 4 independent barrier domains. e-loop with register combine
// (R5). Weights streamed L2->VGPR in A-frag order. Coalesced-read prep.

typedef unsigned short ushort_t;
typedef unsigned int u32;
typedef unsigned long long u64;
typedef __attribute__((ext_vector_type(8))) short short8;
typedef __attribute__((ext_vector_type(4))) float floatx4;
typedef __attribute__((ext_vector_type(16))) float floatx16;
typedef __attribute__((ext_vector_type(4))) int intx4;

// ws layout (bytes); granule = 16 B = 8 bf16 along k
#define W1A_OFF 0u          // per e: granule (kc*16+o)*64+lane, kc<4,  o<16
#define W2A_OFF 524288u     // per e: granule (kc*16+o)*64+lane, kc<32, o<16
#define W3A_OFF 4718592u
#define W4A_OFF 8912896u    // per e: granule (kc*2+o4)*64+lane, kc<32, o4<2
#define XB_OFF  9437184u    // x row-major bf16 [32768][64]
#define B1E_OFF 13631488u   // b1_eff fp32 [8][512]

// LDS layout (bytes): act granules f(row,koct) = (koct>>1)*66+(koct&1)*32+row
#define ACT_OFF 0           // 33 kc rows * 66 granules * 16 B = 34848 (1 kc pad)
#define X_OFF   34848       // 5 kc rows * 66 * 16 = 5280 (1 kc pad)
#define SMEM_SZ 40192

static __device__ __forceinline__ u32 pk2bf(float a, float b) {
  union { __hip_bfloat162 h; u32 u; } v;
  v.h = __float22bfloat162_rn(make_float2(a, b));
  return v.u;
}

static __device__ __forceinline__ float pade_tanh(float x) {
  // tanh x = x(945+105x^2+x^4)/(945+420x^2+15x^4); |err|<=1e-4 for |x|<=2
  float x2 = x * x;
  float num = __builtin_fmaf(x2, __builtin_fmaf(x2, 1.0f, 105.0f), 945.0f);
  float den = __builtin_fmaf(x2, __builtin_fmaf(x2, 15.0f, 420.0f), 945.0f);
  return x * num * __builtin_amdgcn_rcpf(den);
}

static __device__ __forceinline__ void ald16(const void* g, void* l) {
  __builtin_amdgcn_global_load_lds((__attribute__((address_space(1))) void*)g,
                                   (__attribute__((address_space(3))) void*)l,
                                   16, 0, 0);
}

static __device__ __forceinline__ floatx16 mfma32(short8 a, short8 b, floatx16 c) {
  return __builtin_amdgcn_mfma_f32_32x32x16_bf16(a, b, c, 0, 0, 0);
}

// ------------- prep: coalesced reads (thread = (row, k-granule)) ------------
__global__ __launch_bounds__(256) void prep_kernel(
    const float* __restrict__ t, const float* __restrict__ x,
    const float* __restrict__ omega, const float* __restrict__ W1,
    const float* __restrict__ b1, const float* __restrict__ W2,
    const float* __restrict__ W3, const float* __restrict__ W4,
    char* __restrict__ ws) {
  int i = blockIdx.x * 256 + threadIdx.x;
  if (i < 32768) {                       // W1A: e<8, outr<512, kg<8
    int e = i >> 12, rem = i & 4095, outr = rem >> 3, kg = rem & 7;
    const float* s = W1 + (e * 512 + outr) * 67 + kg * 8;  // row stride 67: scalar
    int dest = e * 4096 + ((kg >> 1) * 16 + (outr >> 5)) * 64 + (kg & 1) * 32 + (outr & 31);
    ((intx4*)(ws + W1A_OFF))[dest] = (intx4){
        (int)pk2bf(s[0], s[1]), (int)pk2bf(s[2], s[3]),
        (int)pk2bf(s[4], s[5]), (int)pk2bf(s[6], s[7])};
    return;
  }
  i -= 32768;
  if (i < 262144) {                      // W2A: e<8, outr<512, kg<64
    int e = i >> 15, rem = i & 32767, outr = rem >> 6, kg = rem & 63;
    const floatx4* s = (const floatx4*)(W2 + ((e << 9) + outr) * 512 + (kg << 3));
    floatx4 lo = s[0], hi = s[1];
    int dest = e * 32768 + ((kg >> 1) * 16 + (outr >> 5)) * 64 + (kg & 1) * 32 + (outr & 31);
    ((intx4*)(ws + W2A_OFF))[dest] = (intx4){
        (int)pk2bf(lo[0], lo[1]), (int)pk2bf(lo[2], lo[3]),
        (int)pk2bf(hi[0], hi[1]), (int)pk2bf(hi[2], hi[3])};
    return;
  }
  i -= 262144;
  if (i < 262144) {                      // W3A
    int e = i >> 15, rem = i & 32767, outr = rem >> 6, kg = rem & 63;
    const floatx4* s = (const floatx4*)(W3 + ((e << 9) + outr) * 512 + (kg << 3));
    floatx4 lo = s[0], hi = s[1];
    int dest = e * 32768 + ((kg >> 1) * 16 + (outr >> 5)) * 64 + (kg & 1) * 32 + (outr & 31);
    ((intx4*)(ws + W3A_OFF))[dest] = (intx4){
        (int)pk2bf(lo[0], lo[1]), (int)pk2bf(lo[2], lo[3]),
        (int)pk2bf(hi[0], hi[1]), (int)pk2bf(hi[2], hi[3])};
    return;
  }
  i -= 262144;
  if (i < 32768) {                       // W4A: e<8, outr<64, kg<64
    int e = i >> 12, rem = i & 4095, outr = rem >> 6, kg = rem & 63;
    const floatx4* s = (const floatx4*)(W4 + ((e << 6) + outr) * 512 + (kg << 3));
    floatx4 lo = s[0], hi = s[1];
    int dest = e * 4096 + ((kg >> 1) * 2 + (outr >> 5)) * 64 + (kg & 1) * 32 + (outr & 31);
    ((intx4*)(ws + W4A_OFF))[dest] = (intx4){
        (int)pk2bf(lo[0], lo[1]), (int)pk2bf(lo[2], lo[3]),
        (int)pk2bf(hi[0], hi[1]), (int)pk2bf(hi[2], hi[3])};
    return;
  }
  i -= 32768;
  if (i < 262144) {                      // x -> bf16, row-major
    const floatx4* s = (const floatx4*)(x + i * 8);
    floatx4 lo = s[0], hi = s[1];
    ((intx4*)(ws + XB_OFF))[i] = (intx4){
        (int)pk2bf(lo[0], lo[1]), (int)pk2bf(lo[2], lo[3]),
        (int)pk2bf(hi[0], hi[1]), (int)pk2bf(hi[2], hi[3])};
    return;
  }
  i -= 262144;
  if (i < 4096) {                        // b1_eff: fold t/sin/cos cols of W1
    float tv = t[0];
    int e = i >> 9;
    float om = omega[e];
    ((float*)(ws + B1E_OFF))[i] = b1[i] + tv * W1[i * 67 + 64]
        + sinf(om * tv) * W1[i * 67 + 65] + cosf(om * tv) * W1[i * 67 + 66];
  }
}

// Layer: M=128 feats/wave (o = 4w+ol), N=32 rows. Per kc: 4 A-loads (L2->VGPR),
// 1 B ds_read (depth-1 prefetch), 4 MFMA.
template <int NKC>
static __device__ __forceinline__ void mlp_layer(
    const char* __restrict__ bsrc, char* __restrict__ dst,
    int lane, int w, int q1, int r31,
    const short8* __restrict__ A, const float* __restrict__ bias) {
  const short8* Ap = A + (4 * w) * 64 + lane;   // granule (kc*16 + 4w+ol)*64+lane
  floatx16 acc[4];
#pragma unroll
  for (int ol = 0; ol < 4; ++ol) {
    int fe0 = (4 * w + ol) * 32 + 4 * q1;
#pragma unroll
    for (int g = 0; g < 4; ++g) {
      floatx4 bv = *(const floatx4*)(bias + fe0 + 8 * g);
      acc[ol][4 * g + 0] = bv[0];
      acc[ol][4 * g + 1] = bv[1];
      acc[ol][4 * g + 2] = bv[2];
      acc[ol][4 * g + 3] = bv[3];
    }
  }
  short8 b_c = *(const short8*)(bsrc + (lane << 4));   // B depth-1 prefetch
#pragma unroll 4
  for (int kc = 0; kc < NKC; ++kc) {
    short8 bc = b_c;
    b_c = *(const short8*)(bsrc + (((kc + 1) * 66 + lane) << 4));  // pad row ok
    short8 a0 = Ap[kc * 1024];
    short8 a1 = Ap[kc * 1024 + 64];
    short8 a2 = Ap[kc * 1024 + 128];
    short8 a3 = Ap[kc * 1024 + 192];
    acc[0] = mfma32(a0, bc, acc[0]);
    acc[1] = mfma32(a1, bc, acc[1]);
    acc[2] = mfma32(a2, bc, acc[2]);
    acc[3] = mfma32(a3, bc, acc[3]);
  }
  __syncthreads();                               // all act/x reads done
#pragma unroll
  for (int ol = 0; ol < 4; ++ol) {
    int o_abs = 4 * w + ol;
#pragma unroll
    for (int g = 0; g < 4; ++g) {
      int koct = o_abs * 4 + g;
      char* base = dst + ((((koct >> 1) * 66 + (koct & 1) * 32 + r31) << 4) + q1 * 8);
      float v0 = pade_tanh(acc[ol][4 * g + 0]);
      float v1 = pade_tanh(acc[ol][4 * g + 1]);
      float v2 = pade_tanh(acc[ol][4 * g + 2]);
      float v3 = pade_tanh(acc[ol][4 * g + 3]);
      u32 lo = pk2bf(v0, v1), hi = pk2bf(v2, v3);
      *(u64*)base = ((u64)hi << 32) | lo;
    }
  }
  __syncthreads();                               // act_{n+1} visible
}

__global__ __launch_bounds__(256, 4) void fused_kernel(
    const char* __restrict__ ws, const float* __restrict__ b2,
    const float* __restrict__ b3, const float* __restrict__ b4,
    const float* __restrict__ ew, float* __restrict__ out) {
  __shared__ char smem[SMEM_SZ];
  char* xreg = smem + X_OFF;
  const int t = threadIdx.x, lane = t & 63, w = t >> 6;   // 4 waves
  const int q1 = lane >> 5, r31 = lane & 31;
  const int xcd = blockIdx.x & 7;        // XCD proxy for expert stagger
  const int row0 = blockIdx.x << 5;      // 32-row tile, 1024 blocks

  // stage x once: wave w -> koct pair (2w, 2w+q1), granule w*66 + lane
  const ushort_t* xb = (const ushort_t*)(ws + XB_OFF);
  ald16(xb + (row0 + r31) * 64 + (2 * w + q1) * 8, xreg + w * 1056);

  // L4 assignment: o4 = w&1 (feat half), kh = w>>1 (K half), all 32 rows
  const int o4 = w & 1, kh = w >> 1;
  const int row_l4 = row0 + r31;
  const int fe0 = o4 * 32 + 4 * q1;
  floatx16 out_acc = {};

  __syncthreads();                       // x staged

  const short8* W1A = (const short8*)(ws + W1A_OFF);
  const short8* W2A = (const short8*)(ws + W2A_OFF);
  const short8* W3A = (const short8*)(ws + W3A_OFF);
  const short8* W4A = (const short8*)(ws + W4A_OFF);
  const float* B1E = (const float*)(ws + B1E_OFF);

  for (int ei = 0; ei < 8; ++ei) {
    const int e = (xcd + ei) & 7;
    const float sc = ew[row_l4 * 8 + e];

    mlp_layer<4>(xreg, smem, lane, w, q1, r31, W1A + e * 4096, B1E + e * 512);
    mlp_layer<32>(smem, smem, lane, w, q1, r31, W2A + e * 32768, b2 + e * 512);
    mlp_layer<32>(smem, smem, lane, w, q1, r31, W3A + e * 32768, b3 + e * 512);

    // L4: K-half kh, feat-half o4; acc combined into out_acc with weight sc.
    {
      const short8* Ap = W4A + e * 4096 + o4 * 64 + lane;  // (kc*2+o4)*64+lane
      floatx16 acc = {};
      short8 b_c = *(const short8*)(smem + (((kh * 16) * 66 + lane) << 4));
#pragma unroll 4
      for (int kc = kh * 16; kc < kh * 16 + 16; ++kc) {
        short8 bc = b_c;
        b_c = *(const short8*)(smem + (((kc + 1) * 66 + lane) << 4));  // pad ok
        short8 a = Ap[kc * 128];
        acc = mfma32(a, bc, acc);
      }
      if (kh == 0) {                     // bias added once (kh=0 partner)
        const float* bp = b4 + e * 64 + fe0;
#pragma unroll
        for (int g = 0; g < 4; ++g) {
          floatx4 bv = *(const floatx4*)(bp + 8 * g);
          out_acc[4 * g + 0] += sc * (acc[4 * g + 0] + bv[0]);
          out_acc[4 * g + 1] += sc * (acc[4 * g + 1] + bv[1]);
          out_acc[4 * g + 2] += sc * (acc[4 * g + 2] + bv[2]);
          out_acc[4 * g + 3] += sc * (acc[4 * g + 3] + bv[3]);
        }
      } else {
#pragma unroll
        for (int i = 0; i < 16; ++i) out_acc[i] += sc * acc[i];
      }
    }
  }

  // merge K-half partners (w, w+2) via LDS (act dead), plain stores
  __syncthreads();
  if (w >= 2) {
#pragma unroll
    for (int i = 0; i < 4; ++i) {
      floatx4 p = {out_acc[i * 4 + 0], out_acc[i * 4 + 1],
                   out_acc[i * 4 + 2], out_acc[i * 4 + 3]};
      *(floatx4*)(smem + (w - 2) * 4096 + i * 1024 + lane * 16) = p;
    }
  }
  __syncthreads();
  if (w < 2) {
    float* orow = out + row_l4 * 64 + fe0;
#pragma unroll
    for (int g = 0; g < 4; ++g) {
      floatx4 p = *(const floatx4*)(smem + w * 4096 + g * 1024 + lane * 16);
      floatx4 v = {out_acc[4 * g + 0] + p[0], out_acc[4 * g + 1] + p[1],
                   out_acc[4 * g + 2] + p[2], out_acc[4 * g + 3] + p[3]};
      *(floatx4*)(orow + 8 * g) = v;
    }
  }
}

extern "C" void kernel_launch(void* const* d_in, const int* in_sizes, int n_in,
                              void* d_out, int out_size, void* d_ws, size_t ws_size,
                              hipStream_t stream) {
  const float* t  = (const float*)d_in[0];
  const float* x  = (const float*)d_in[1];
  const float* ew = (const float*)d_in[2];
  const float* om = (const float*)d_in[3];
  const float* W1 = (const float*)d_in[4];
  const float* b1 = (const float*)d_in[5];
  const float* W2 = (const float*)d_in[6];
  const float* b2 = (const float*)d_in[7];
  const float* W3 = (const float*)d_in[8];
  const float* b3 = (const float*)d_in[9];
  const float* W4 = (const float*)d_in[10];
  const float* b4 = (const float*)d_in[11];
  char* ws = (char*)d_ws;
  float* out = (float*)d_out;
  (void)in_sizes; (void)n_in; (void)ws_size; (void)out_size;

  // granule threads: 32768+262144+262144+32768+262144+4096 = 856064 = 3344*256
  prep_kernel<<<3344, 256, 0, stream>>>(t, x, om, W1, b1, W2, W3, W4, ws);
  fused_kernel<<<1024, 256, 0, stream>>>(ws, b2, b3, b4, ew, out);
}